// Round 1
// baseline (1223.075 us; speedup 1.0000x reference)
//
#include <hip/hip_runtime.h>
#include <stdint.h>

#define D_IN 1024
#define M_SAE 16384
#define NROWS 4096
#define NTOT 67108864     // NROWS * M_SAE
#define K_TOTAL 262144

// ---- workspace layout (bytes) ----
#define META_OFF    0            // 4 KB of u32: [0]=cand_count [1]=B_bin [2]=cum_above
                                 // [3]=cutoff_bits [4]=count_gt [5]=need [6]=tie_cnt
                                 // [8..72)=tie indices, [72]=float sum (atomic)
#define GHIST_OFF   4096         // 16384 u32
#define ROWCNT_OFF  69632        // 4096 u32
#define CAND_OFF    86016        // CAND_CAP x uint2
#define CAND_CAP    262144
#define BHIST_OFF   2183168      // 256 * 16384 u32
#define ROWLIST_OFF 18960384     // 4096 * ROW_CAP * uint2
#define ROW_CAP     512
#define XBF_OFF     35737600     // 4096*1024 bf16
#define WBT_OFF     44126208     // 16384*1024 bf16 (transposed W_enc)

typedef __bf16 bf16x8 __attribute__((ext_vector_type(8)));
typedef float  f32x4  __attribute__((ext_vector_type(4)));

__device__ __forceinline__ unsigned short f2bf(float f) {
    uint32_t u = __float_as_uint(f);
    uint32_t r = u + 0x7FFFu + ((u >> 16) & 1u);   // RNE
    return (unsigned short)(r >> 16);
}

// ---- convert x to bf16 ----
__global__ void conv_x(const float* __restrict__ in, unsigned short* __restrict__ out, int n4) {
    int i = blockIdx.x * blockDim.x + threadIdx.x;
    int stride = gridDim.x * blockDim.x;
    const float4* in4 = (const float4*)in;
    ushort4* out4 = (ushort4*)out;
    for (; i < n4; i += stride) {
        float4 v = in4[i];
        ushort4 o;
        o.x = f2bf(v.x); o.y = f2bf(v.y); o.z = f2bf(v.z); o.w = f2bf(v.w);
        out4[i] = o;
    }
}

// ---- convert + transpose W_enc [1024][16384] -> wT bf16 [16384][1024] ----
__global__ __launch_bounds__(256) void conv_wT(const float* __restrict__ w,
                                               unsigned short* __restrict__ wT) {
    __shared__ unsigned short tile[64][65];
    int n0 = blockIdx.x * 64, k0 = blockIdx.y * 64;
    int c = threadIdx.x & 63;
    int r4 = threadIdx.x >> 6;   // 0..3
    #pragma unroll
    for (int rr = 0; rr < 16; rr++) {
        int kl = r4 * 16 + rr;
        tile[c][kl] = f2bf(w[(size_t)(k0 + kl) * M_SAE + n0 + c]);
    }
    __syncthreads();
    #pragma unroll
    for (int rr = 0; rr < 16; rr++) {
        int nl = r4 * 16 + rr;
        wT[(size_t)(n0 + nl) * D_IN + k0 + c] = tile[nl][c];
    }
}

// ---- bf16 MFMA encode GEMM: a = relu(x @ W_enc + b_enc), fp32 out ----
__global__ __launch_bounds__(256) void gemm_encode(
    const unsigned short* __restrict__ xb,  // [4096][1024] bf16
    const unsigned short* __restrict__ wT,  // [16384][1024] bf16 (n-major)
    const float* __restrict__ be,
    float* __restrict__ aout)               // [4096][16384] fp32
{
    __shared__ unsigned short As[128 * 40];  // [m][k], pad 32->40 (2-way bank alias = free)
    __shared__ unsigned short Bs[128 * 40];  // [n][k]
    const int tid  = threadIdx.x;
    const int lane = tid & 63;
    const int wv   = tid >> 6;
    const int wRow = (wv & 1) * 64;
    const int wCol = (wv >> 1) * 64;
    const int q    = lane >> 4;
    const int l16  = lane & 15;
    const int row0 = blockIdx.y * 128;
    const int col0 = blockIdx.x * 128;

    f32x4 acc[4][4];
    #pragma unroll
    for (int i = 0; i < 4; i++)
        #pragma unroll
        for (int j = 0; j < 4; j++) { f32x4 z = {0.f, 0.f, 0.f, 0.f}; acc[i][j] = z; }

    for (int k0 = 0; k0 < D_IN; k0 += 32) {
        #pragma unroll
        for (int i = 0; i < 2; i++) {
            int f = i * 256 + tid;
            int r = f >> 2, kq = f & 3;
            *(uint4*)&As[r * 40 + kq * 8] =
                *(const uint4*)(xb + (size_t)(row0 + r) * D_IN + k0 + kq * 8);
            *(uint4*)&Bs[r * 40 + kq * 8] =
                *(const uint4*)(wT + (size_t)(col0 + r) * D_IN + k0 + kq * 8);
        }
        __syncthreads();
        bf16x8 af[4], bfr[4];
        #pragma unroll
        for (int i = 0; i < 4; i++)
            af[i] = *(const bf16x8*)&As[(wRow + 16 * i + l16) * 40 + q * 8];
        #pragma unroll
        for (int j = 0; j < 4; j++)
            bfr[j] = *(const bf16x8*)&Bs[(wCol + 16 * j + l16) * 40 + q * 8];
        #pragma unroll
        for (int i = 0; i < 4; i++)
            #pragma unroll
            for (int j = 0; j < 4; j++)
                acc[i][j] = __builtin_amdgcn_mfma_f32_16x16x32_bf16(af[i], bfr[j], acc[i][j], 0, 0, 0);
        __syncthreads();
    }
    #pragma unroll
    for (int i = 0; i < 4; i++) {
        #pragma unroll
        for (int j = 0; j < 4; j++) {
            int col = col0 + wCol + 16 * j + l16;
            float bias = be[col];
            #pragma unroll
            for (int r = 0; r < 4; r++) {
                int row = row0 + wRow + 16 * i + q * 4 + r;
                float v = acc[i][j][r] + bias;
                aout[(size_t)row * M_SAE + col] = v > 0.f ? v : 0.f;
            }
        }
    }
}

// ---- 14-bit histogram of positive float bits (bits>>17), per-block LDS ----
__global__ __launch_bounds__(1024) void hist_kernel(const float4* __restrict__ a4,
                                                    uint32_t* __restrict__ bhist) {
    __shared__ uint32_t h[16384];
    for (int i = threadIdx.x; i < 16384; i += 1024) h[i] = 0;
    __syncthreads();
    int idx = blockIdx.x * 65536 + threadIdx.x;
    for (int it = 0; it < 64; it++, idx += 1024) {
        float4 v = a4[idx];
        if (v.x > 0.f) atomicAdd(&h[__float_as_uint(v.x) >> 17], 1u);
        if (v.y > 0.f) atomicAdd(&h[__float_as_uint(v.y) >> 17], 1u);
        if (v.z > 0.f) atomicAdd(&h[__float_as_uint(v.z) >> 17], 1u);
        if (v.w > 0.f) atomicAdd(&h[__float_as_uint(v.w) >> 17], 1u);
    }
    __syncthreads();
    uint32_t* dst = bhist + (size_t)blockIdx.x * 16384;
    for (int i = threadIdx.x; i < 16384; i += 1024) dst[i] = h[i];
}

__global__ void hist_reduce(const uint32_t* __restrict__ bhist, uint32_t* __restrict__ gh) {
    int bin = blockIdx.x * 256 + threadIdx.x;
    uint32_t s = 0;
    for (int r = 0; r < 256; r++) s += bhist[(size_t)r * 16384 + bin];
    gh[bin] = s;
}

// ---- find the coarse bin containing the k-th largest ----
__global__ __launch_bounds__(256) void find_bin(const uint32_t* __restrict__ gh,
                                                uint32_t* __restrict__ meta) {
    __shared__ uint32_t csum[256];
    __shared__ uint32_t pfx[257];
    int t = threadIdx.x;
    int hi = 16384 - 64 * t;             // chunk t covers [hi-64, hi), descending value order
    uint32_t s = 0;
    for (int i = 0; i < 64; i++) s += gh[hi - 64 + i];
    csum[t] = s;
    __syncthreads();
    if (t == 0) {
        uint32_t c = 0;
        for (int i = 0; i < 256; i++) { pfx[i] = c; c += csum[i]; }
        pfx[256] = c;
    }
    __syncthreads();
    uint32_t above = pfx[t];
    if (above < K_TOTAL && above + csum[t] >= K_TOTAL) {
        uint32_t cum = above;
        for (int b = hi - 1; b >= hi - 64; b--) {
            uint32_t h = gh[b];
            if (cum + h >= K_TOTAL) { meta[1] = (uint32_t)b; meta[2] = cum; break; }
            cum += h;
        }
    }
}

// ---- compact all elements in the cutoff bin ----
__global__ __launch_bounds__(256) void compact_kernel(const float4* __restrict__ a4,
                                                      uint32_t* __restrict__ meta,
                                                      uint2* __restrict__ cand) {
    uint32_t Bb = meta[1];
    int idx = blockIdx.x * 256 + threadIdx.x;
    for (int it = 0; it < 64; it++) {
        int i4 = idx + it * 262144;
        float4 v = a4[i4];
        uint32_t base = (uint32_t)i4 * 4u;
        uint32_t u;
        u = __float_as_uint(v.x);
        if (v.x > 0.f && (u >> 17) == Bb) { uint32_t p = atomicAdd(&meta[0], 1u); if (p < CAND_CAP) cand[p] = make_uint2(base + 0, u); }
        u = __float_as_uint(v.y);
        if (v.y > 0.f && (u >> 17) == Bb) { uint32_t p = atomicAdd(&meta[0], 1u); if (p < CAND_CAP) cand[p] = make_uint2(base + 1, u); }
        u = __float_as_uint(v.z);
        if (v.z > 0.f && (u >> 17) == Bb) { uint32_t p = atomicAdd(&meta[0], 1u); if (p < CAND_CAP) cand[p] = make_uint2(base + 2, u); }
        u = __float_as_uint(v.w);
        if (v.w > 0.f && (u >> 17) == Bb) { uint32_t p = atomicAdd(&meta[0], 1u); if (p < CAND_CAP) cand[p] = make_uint2(base + 3, u); }
    }
}

// ---- exact 32-bit cutoff + tie selection within the candidate bin ----
__global__ __launch_bounds__(1024) void refine_kernel(const uint2* __restrict__ cand,
                                                      uint32_t* __restrict__ meta) {
    __shared__ uint32_t h1[512];
    __shared__ uint32_t h2[256];
    __shared__ uint32_t sS, scum2, tie_n;
    __shared__ uint32_t ties[64];
    int t = threadIdx.x;
    uint32_t n = meta[0]; if (n > CAND_CAP) n = CAND_CAP;
    uint32_t cum_above = meta[2];
    if (t < 512) h1[t] = 0;
    if (t < 256) h2[t] = 0;
    if (t == 0) tie_n = 0;
    __syncthreads();
    for (uint32_t i = t; i < n; i += 1024) {
        uint32_t bits = cand[i].y;
        atomicAdd(&h1[(bits >> 8) & 511], 1u);
    }
    __syncthreads();
    if (t == 0) {
        uint32_t cum = cum_above; uint32_t S = 0;
        for (int s = 511; s >= 0; s--) {
            if (cum + h1[s] >= K_TOTAL) { S = (uint32_t)s; break; }
            cum += h1[s];
        }
        sS = S; scum2 = cum;
    }
    __syncthreads();
    uint32_t S = sS;
    for (uint32_t i = t; i < n; i += 1024) {
        uint32_t bits = cand[i].y;
        if (((bits >> 8) & 511) == S) atomicAdd(&h2[bits & 255], 1u);
    }
    __syncthreads();
    if (t == 0) {
        uint32_t cum = scum2; uint32_t L = 0;
        for (int l = 255; l >= 0; l--) {
            if (cum + h2[l] >= K_TOTAL) { L = (uint32_t)l; break; }
            cum += h2[l];
        }
        uint32_t cutoff = (meta[1] << 17) | (S << 8) | L;
        meta[3] = cutoff;
        meta[4] = cum;               // count strictly greater
        meta[5] = K_TOTAL - cum;     // ties needed
    }
    __syncthreads();
    uint32_t cutoff = meta[3];
    for (uint32_t i = t; i < n; i += 1024) {
        if (cand[i].y == cutoff) {
            uint32_t p = atomicAdd(&tie_n, 1u);
            if (p < 64) ties[p] = cand[i].x;
        }
    }
    __syncthreads();
    if (t == 0) {
        uint32_t tn = tie_n; if (tn > 64) tn = 64;
        for (uint32_t i = 1; i < tn; i++) {          // sort tie indices ascending
            uint32_t v = ties[i]; int j = (int)i - 1;
            while (j >= 0 && ties[j] > v) { ties[j + 1] = ties[j]; j--; }
            ties[j + 1] = v;
        }
        uint32_t need = meta[5]; if (need > tn) need = tn;
        meta[6] = need;
        for (uint32_t i = 0; i < need; i++) meta[8 + i] = ties[i];
    }
}

// ---- threshold z in place, build per-row lists, accumulate sum ----
__global__ __launch_bounds__(256) void zbuild(float* __restrict__ z,
                                              const uint32_t* __restrict__ meta,
                                              uint32_t* __restrict__ rowcnt,
                                              uint2* __restrict__ rowlist,
                                              float* __restrict__ sum_out) {
    float cutoff = __uint_as_float(meta[3]);
    uint32_t cutoff_bits = meta[3];
    uint32_t tcnt = meta[6];
    float lsum = 0.f;
    float4* z4 = (float4*)z;
    int base_idx = blockIdx.x * 256 + threadIdx.x;
    for (int it = 0; it < 32; it++) {
        int i4 = base_idx + it * 524288;
        float4 v = z4[i4];
        uint32_t gbase = (uint32_t)i4 * 4u;
        float4 o;
        float* vp = &v.x; float* op = &o.x;
        #pragma unroll
        for (int c = 0; c < 4; c++) {
            float val = vp[c];
            bool keep = val > cutoff;
            if (!keep && val == cutoff && tcnt) {
                uint32_t gi = gbase + (uint32_t)c;
                for (uint32_t j = 0; j < tcnt; j++)
                    if (meta[8 + j] == gi) { keep = true; break; }
            }
            if (keep) {
                uint32_t gi = gbase + (uint32_t)c;
                uint32_t r = gi >> 14;
                uint32_t pos = atomicAdd(&rowcnt[r], 1u);
                if (pos < ROW_CAP)
                    rowlist[(size_t)r * ROW_CAP + pos] = make_uint2(gi & 16383u, __float_as_uint(val));
                lsum += val;
                op[c] = val;
            } else {
                op[c] = 0.f;
            }
        }
        z4[i4] = o;
        (void)cutoff_bits;
    }
    #pragma unroll
    for (int off = 32; off > 0; off >>= 1) lsum += __shfl_down(lsum, off);
    if ((threadIdx.x & 63) == 0 && lsum != 0.f) atomicAdd(sum_out, lsum);
}

// ---- sparse decode: x_hat[row] = sum val * W_dec[col] + b_dec ----
__global__ __launch_bounds__(256) void decode(const uint32_t* __restrict__ rowcnt,
                                              const uint2* __restrict__ rowlist,
                                              const float* __restrict__ wdec,
                                              const float* __restrict__ bdec,
                                              float* __restrict__ xhat) {
    __shared__ uint2 buf[256];
    int row = blockIdx.x;
    int t = threadIdx.x;
    uint32_t n = rowcnt[row]; if (n > ROW_CAP) n = ROW_CAP;
    float4 acc = *(const float4*)(bdec + t * 4);
    const uint2* lst = rowlist + (size_t)row * ROW_CAP;
    for (uint32_t base = 0; base < n; base += 256) {
        uint32_t m = n - base; if (m > 256) m = 256;
        __syncthreads();
        if ((uint32_t)t < m) buf[t] = lst[base + t];
        __syncthreads();
        for (uint32_t j = 0; j < m; j++) {
            uint2 p = buf[j];
            float val = __uint_as_float(p.y);
            const float4 wv = *(const float4*)(wdec + (size_t)p.x * D_IN + t * 4);
            acc.x += val * wv.x; acc.y += val * wv.y;
            acc.z += val * wv.z; acc.w += val * wv.w;
        }
    }
    *(float4*)(xhat + (size_t)row * D_IN + t * 4) = acc;
}

__global__ void scalars_kernel(const uint32_t* __restrict__ meta, float* __restrict__ out) {
    uint32_t nnz = meta[4] + meta[6];
    float sum = ((const float*)meta)[72];
    out[0] = (float)nnz / (float)NTOT;
    out[1] = sum / fmaxf((float)nnz, 1.0f);
    out[2] = (float)nnz;
}

extern "C" void kernel_launch(void* const* d_in, const int* in_sizes, int n_in,
                              void* d_out, int out_size, void* d_ws, size_t ws_size,
                              hipStream_t stream) {
    (void)in_sizes; (void)n_in; (void)out_size; (void)ws_size;
    const float* x     = (const float*)d_in[0];
    const float* W_enc = (const float*)d_in[1];
    const float* b_enc = (const float*)d_in[2];
    const float* W_dec = (const float*)d_in[3];
    const float* b_dec = (const float*)d_in[4];

    float* out  = (float*)d_out;
    float* xhat = out;
    float* z    = out + 4194304;                 // [4096][16384], also scratch for `a`
    float* scal = out + 4194304 + 67108864;

    uint8_t* ws = (uint8_t*)d_ws;
    uint32_t* meta        = (uint32_t*)(ws + META_OFF);
    uint32_t* ghist       = (uint32_t*)(ws + GHIST_OFF);
    uint32_t* rowcnt      = (uint32_t*)(ws + ROWCNT_OFF);
    uint2*    cand        = (uint2*)(ws + CAND_OFF);
    uint32_t* bhist       = (uint32_t*)(ws + BHIST_OFF);
    uint2*    rowlist     = (uint2*)(ws + ROWLIST_OFF);
    unsigned short* xb    = (unsigned short*)(ws + XBF_OFF);
    unsigned short* wT    = (unsigned short*)(ws + WBT_OFF);

    hipMemsetAsync(ws, 0, 86016, stream);
    conv_x<<<1024, 256, 0, stream>>>(x, xb, 1048576);
    conv_wT<<<dim3(256, 16), 256, 0, stream>>>(W_enc, wT);
    gemm_encode<<<dim3(128, 32), 256, 0, stream>>>(xb, wT, b_enc, z);
    hist_kernel<<<256, 1024, 0, stream>>>((const float4*)z, bhist);
    hist_reduce<<<64, 256, 0, stream>>>(bhist, ghist);
    find_bin<<<1, 256, 0, stream>>>(ghist, meta);
    compact_kernel<<<1024, 256, 0, stream>>>((const float4*)z, meta, cand);
    refine_kernel<<<1, 1024, 0, stream>>>(cand, meta);
    zbuild<<<2048, 256, 0, stream>>>(z, meta, rowcnt, rowlist, (float*)(meta + 72));
    decode<<<4096, 256, 0, stream>>>(rowcnt, rowlist, W_dec, b_dec, xhat);
    scalars_kernel<<<1, 1, 0, stream>>>(meta, scal);
}